// Round 11
// baseline (756.787 us; speedup 1.0000x reference)
//
#include <hip/hip_runtime.h>
#include <math.h>

#define B_ 8192
#define L_ 49
#define C_ 512
#define R_ 128

typedef short   bf16x8 __attribute__((ext_vector_type(8)));
typedef unsigned short u16x8 __attribute__((ext_vector_type(8)));
typedef float   f32x4  __attribute__((ext_vector_type(4)));

// ws layout (ushort elements) — ALL weights wave-fragment-contiguous
#define WS_LWF   0           // 65536  [nt=8][ks=16][lane=64][8]
#define WS_WB3F  65536       // 36864  [tap=9][f=4][ks=2][lane=64][8]
#define WS_WB5F  102400      // 102400 [tap=25][f=4][ks=2][lane=64][8]
#define WS_GWF   204800      // 65536  like lwf
#define WS_CWF   270336      // 65536  [nf=32][ks=4][lane=64][8]

// LDS layout (bytes), total 76960
#define SM_XB    0           // ush[49][256] swizzled = 25088 | overlay P5: f32 part[2][49*33]
#define SM_XLP   25088       // ush[121][136] padded x_l image = 32912
#define SM_MAXB  58000       // bf16[8][256] = 4096
#define SM_SUMF  62096       // f32[8][256] = 8192
#define SM_GA    70288       // bf16[2][256] = 1024
#define SM_G     71312       // f32[2][128] = 1024
#define SM_HB    72336       // bf16[128] = 256
#define SM_CA    72592       // f32[512] = 2048
#define SM_SPW   74640       // f32[4][64] = 1024 (region holds 2048)
#define SM_SP    76688       // f32[64] = 256
#define SM_GDOT  76944       // f32[4] = 16
#define SM_TOT   76960

#define XLP_N    16456       // 121*136 ushorts
#define DBIAS    3264        // (2*11+2)*136
#define PARTN    1617        // 49*33 f32 per conv5 partial plane

__device__ __forceinline__ float bf2f(unsigned short u) {
    union { float f; unsigned int i; } v; v.i = ((unsigned int)u) << 16; return v.f;
}
__device__ __forceinline__ unsigned short f2bf(float f) {
    union { float f; unsigned int i; } v; v.f = f;
    unsigned int r = v.i + 0x7fffu + ((v.i >> 16) & 1u);
    return (unsigned short)(r >> 16);
}
__device__ __forceinline__ unsigned int pkbf(float a, float b) {
    unsigned int r;
    asm("v_cvt_pk_bf16_f32 %0, %1, %2" : "=v"(r) : "v"(a), "v"(b));
    return r;
}
__device__ __forceinline__ float star_relu(float x, float sc, float bi) {
    float r = fmaxf(x, 0.f);
    return sc * r * r + bi;
}
__device__ __forceinline__ float sigmoidf_(float x) {
    return 1.f / (1.f + __expf(-x));
}
__device__ __forceinline__ int prowf(int lp) {
    int pi = lp / 7, pj = lp - pi * 7;
    return (pi + 2) * 11 + (pj + 2);
}

// ---------------- pre-pass: convert + repack weights ----------------
__global__ void cvt_weights(const float* __restrict__ lw, const float* __restrict__ w3,
                            const float* __restrict__ w5, const float* __restrict__ gw,
                            const float* __restrict__ cw, unsigned short* __restrict__ ws)
{
    int t = blockIdx.x * blockDim.x + threadIdx.x;
    int stride = gridDim.x * blockDim.x;
    for (int i = t; i < 65536; i += stride) {
        int j = i & 7, lane = (i >> 3) & 63, ks = (i >> 9) & 15, nt = i >> 13;
        int n = nt * 16 + (lane & 15);
        int k = ks * 32 + (lane >> 4) * 8 + j;
        ws[WS_LWF + i] = f2bf(lw[n * 512 + k]);
        ws[WS_GWF + i] = f2bf(gw[n * 512 + k]);
    }
    for (int i = t; i < 65536; i += stride) {
        int j = i & 7, lane = (i >> 3) & 63, ks = (i >> 9) & 3, nf = i >> 11;
        int c = nf * 16 + (lane & 15);
        int k = ks * 32 + (lane >> 4) * 8 + j;
        ws[WS_CWF + i] = f2bf(cw[c * 128 + k]);
    }
    for (int i = t; i < 36864; i += stride) {
        int j = i & 7, lane = (i >> 3) & 63, ks = (i >> 9) & 1, f = (i >> 10) & 3, tap = i >> 12;
        int oc = f * 16 + (lane & 15);
        int ic = ks * 32 + (lane >> 4) * 8 + j;
        ws[WS_WB3F + i] = f2bf(w3[(oc * 64 + ic) * 9 + tap]);
    }
    for (int i = t; i < 102400; i += stride) {
        int j = i & 7, lane = (i >> 3) & 63, ks = (i >> 9) & 1, f = (i >> 10) & 3, tap = i >> 12;
        int oc = f * 16 + (lane & 15);
        int ic = ks * 32 + (lane >> 4) * 8 + j;
        ws[WS_WB5F + i] = f2bf(w5[(oc * 64 + ic) * 25 + tap]);
    }
}

// ---------------- conv tap-GEMM, nf=2: one A-read feeds 2 MFMA ----------------
template <int KD, int PAD, int COLBASE, int T0, int T1>
__device__ __forceinline__ void conv2(const unsigned short* __restrict__ s_xlp,
                                      const unsigned short* __restrict__ wtbf,
                                      int m16, int kg, int ln, int nf0, f32x4 C[4][2])
{
    int base[4];
    #pragma unroll
    for (int mf = 0; mf < 4; ++mf) {
        int lp = min(mf * 16 + m16, 48);
        base[mf] = prowf(lp) * 136 + COLBASE + kg * 8 - DBIAS;
    }
    #pragma unroll
    for (int tap = T0; tap < T1; ++tap) {
        const int doff = ((tap / KD - PAD) * 11 + (tap % KD - PAD)) * 136 + DBIAS;
        #pragma unroll
        for (int ks = 0; ks < 2; ++ks) {
            bf16x8 bb0 = *(const bf16x8*)(wtbf + ((tap * 4 + nf0)     * 2 + ks) * 512 + ln * 8);
            bf16x8 bb1 = *(const bf16x8*)(wtbf + ((tap * 4 + nf0 + 1) * 2 + ks) * 512 + ln * 8);
            #pragma unroll
            for (int mf = 0; mf < 4; ++mf) {
                bf16x8 a = *(const bf16x8*)&s_xlp[base[mf] + doff + ks * 32];
                C[mf][0] = __builtin_amdgcn_mfma_f32_16x16x32_bf16(a, bb0, C[mf][0], 0, 0, 0);
                C[mf][1] = __builtin_amdgcn_mfma_f32_16x16x32_bf16(a, bb1, C[mf][1], 0, 0, 0);
            }
        }
    }
}

// ---------------- main fused kernel ----------------
__global__ __launch_bounds__(512, 4)
void mafn_fused(const float* __restrict__ x,
                const float* __restrict__ b3, const float* __restrict__ b5,
                const float* __restrict__ cb, const float* __restrict__ sw,
                const float* __restrict__ sb, const float* __restrict__ ssc,
                const float* __restrict__ sbi,
                const unsigned short* __restrict__ ws,
                float* __restrict__ out)
{
    __shared__ __align__(16) unsigned char smem[SM_TOT];
    unsigned short* s_xb   = (unsigned short*)(smem + SM_XB);
    float*          s_part = (float*)(smem + SM_XB);            // overlay (xb dead after P3)
    unsigned short* s_xlp  = (unsigned short*)(smem + SM_XLP);
    unsigned short* s_maxb = (unsigned short*)(smem + SM_MAXB);
    float*          s_sumf = (float*)(smem + SM_SUMF);
    unsigned short* s_ga   = (unsigned short*)(smem + SM_GA);
    float*          s_g    = (float*)(smem + SM_G);
    unsigned short* s_hb   = (unsigned short*)(smem + SM_HB);
    float*          s_ca   = (float*)(smem + SM_CA);
    float*          s_spw  = (float*)(smem + SM_SPW);
    float*          s_sp   = (float*)(smem + SM_SP);
    float*          s_gdot = (float*)(smem + SM_GDOT);

    const int b = blockIdx.x, t = threadIdx.x;
    const int wv = t >> 6, ln = t & 63;
    const int m16 = ln & 15, kg = ln >> 4;
    const float scale = ssc[0], sbias = sbi[0];

    const unsigned short* lwf  = ws + WS_LWF;
    const unsigned short* wb3f = ws + WS_WB3F;
    const unsigned short* wb5f = ws + WS_WB5F;
    const unsigned short* gwf  = ws + WS_GWF;
    const unsigned short* cwf  = ws + WS_CWF;

    // P3 role: waves 0-3 -> rows 0-31 + g-GEMM; waves 4-7 -> rows 32-48
    const int mfbase = (wv >= 4) ? 2 : 0;
    const int nfp = (wv & 3) * 2;           // x_l n-fragment pair {nfp, nfp+1}

    f32x4 accA[2][2];                        // [mf2][q]
    f32x4 accG[2];                           // waves 0-3 only
    {
        const f32x4 z = {0.f, 0.f, 0.f, 0.f};
        accA[0][0] = z; accA[0][1] = z; accA[1][0] = z; accA[1][1] = z;
        accG[0] = z; accG[1] = z;
    }

    // zero padded x_l image (borders stay 0)
    for (int i = t; i < XLP_N / 2; i += 512) ((unsigned int*)s_xlp)[i] = 0;

    const int l0 = wv * 6;
    const int nl = (wv < 7) ? 6 : 7;

    // ================= K-split halves =================
    #pragma unroll 1
    for (int h = 0; h < 2; ++h) {
        // ---- P1: load x half, partials, bf16 -> swizzled LDS ----
        {
            const float4* x4 = (const float4*)(x + (size_t)b * (L_ * C_)) + h * 64;
            float4 mx = {-3.4e38f, -3.4e38f, -3.4e38f, -3.4e38f};
            float4 sm = {0.f, 0.f, 0.f, 0.f};
            for (int li = 0; li < nl; ++li) {
                int l = l0 + li;
                float4 v = x4[l * 128 + ln];
                mx.x = fmaxf(mx.x, v.x); mx.y = fmaxf(mx.y, v.y);
                mx.z = fmaxf(mx.z, v.z); mx.w = fmaxf(mx.w, v.w);
                sm.x += v.x; sm.y += v.y; sm.z += v.z; sm.w += v.w;
                uint2 p; p.x = pkbf(v.x, v.y); p.y = pkbf(v.z, v.w);
                int chunk = (ln >> 1) ^ (l & 7);
                *(uint2*)&s_xb[l * 256 + chunk * 8 + (ln & 1) * 4] = p;
            }
            uint2 pm; pm.x = pkbf(mx.x, mx.y); pm.y = pkbf(mx.z, mx.w);
            *(uint2*)&s_maxb[wv * 256 + ln * 4] = pm;
            *(float4*)&s_sumf[wv * 256 + ln * 4] = sm;
        }
        __syncthreads();

        // ---- P2: finalize max/avg for this half ----
        {
            if (t < 256) {
                int c = t;
                float m = bf2f(s_maxb[c]);
                #pragma unroll
                for (int i = 1; i < 8; ++i) m = fmaxf(m, bf2f(s_maxb[i * 256 + c]));
                s_ga[c] = f2bf(m);
            } else {
                int c = t - 256;
                float s = 0.f;
                #pragma unroll
                for (int i = 0; i < 8; ++i) s += s_sumf[i * 256 + c];
                s_ga[256 + c] = f2bf(s * (1.f / 49.f));
            }
        }
        __syncthreads();

        // ---- P3: x_l GEMM (M-split, nf=2) + g-GEMM (waves 0-3) ----
        {
            int rowA[2];
            #pragma unroll
            for (int mf2 = 0; mf2 < 2; ++mf2)
                rowA[mf2] = min((mfbase + mf2) * 16 + m16, 48);
            #pragma unroll 2
            for (int ks = 0; ks < 8; ++ks) {
                bf16x8 bb0 = *(const bf16x8*)(lwf + ((nfp)     * 16 + h * 8 + ks) * 512 + ln * 8);
                bf16x8 bb1 = *(const bf16x8*)(lwf + ((nfp + 1) * 16 + h * 8 + ks) * 512 + ln * 8);
                #pragma unroll
                for (int mf2 = 0; mf2 < 2; ++mf2) {
                    int chunk = (ks * 4 + kg) ^ (rowA[mf2] & 7);
                    bf16x8 a = *(const bf16x8*)&s_xb[rowA[mf2] * 256 + chunk * 8];
                    accA[mf2][0] = __builtin_amdgcn_mfma_f32_16x16x32_bf16(a, bb0, accA[mf2][0], 0, 0, 0);
                    accA[mf2][1] = __builtin_amdgcn_mfma_f32_16x16x32_bf16(a, bb1, accA[mf2][1], 0, 0, 0);
                }
            }
            if (wv < 4) {
                const bf16x8 zz = {0,0,0,0,0,0,0,0};
                #pragma unroll 2
                for (int ks = 0; ks < 8; ++ks) {
                    bf16x8 a = (m16 < 2) ? *(const bf16x8*)&s_ga[m16 * 256 + ks * 32 + kg * 8] : zz;
                    bf16x8 gb0 = *(const bf16x8*)(gwf + ((nfp)     * 16 + h * 8 + ks) * 512 + ln * 8);
                    bf16x8 gb1 = *(const bf16x8*)(gwf + ((nfp + 1) * 16 + h * 8 + ks) * 512 + ln * 8);
                    accG[0] = __builtin_amdgcn_mfma_f32_16x16x32_bf16(a, gb0, accG[0], 0, 0, 0);
                    accG[1] = __builtin_amdgcn_mfma_f32_16x16x32_bf16(a, gb1, accG[1], 0, 0, 0);
                }
            }
        }
        __syncthreads();
    }

    // ---- P4: store x_l into padded image; g/hb from waves 0-3 ----
    {
        const int nb = nfp * 16 + m16;
        #pragma unroll
        for (int mf2 = 0; mf2 < 2; ++mf2) {
            #pragma unroll
            for (int q = 0; q < 2; ++q) {
                #pragma unroll
                for (int rp = 0; rp < 2; ++rp) {
                    unsigned int u = pkbf(accA[mf2][q][rp * 2], accA[mf2][q][rp * 2 + 1]);
                    int lp0 = (mfbase + mf2) * 16 + kg * 4 + rp * 2;
                    if (lp0 < 49)     s_xlp[prowf(lp0) * 136 + nb + q * 16]     = (unsigned short)u;
                    if (lp0 + 1 < 49) s_xlp[prowf(lp0 + 1) * 136 + nb + q * 16] = (unsigned short)(u >> 16);
                }
            }
        }
        if (wv < 4 && kg == 0) {
            #pragma unroll
            for (int q = 0; q < 2; ++q) {
                int n = (nfp + q) * 16 + m16;
                float g1v = star_relu(accG[q][0], scale, sbias);
                float g2v = star_relu(accG[q][1], scale, sbias);
                s_g[n] = g1v;
                s_g[128 + n] = g2v;
                s_hb[n] = f2bf(g1v + g2v);
            }
        }
    }
    __syncthreads();

    // ---- P5a: convs (nf=2, conv5 tap-split) / c_aggr / gdot ----
    f32x4 C[4][2];
    {
        const f32x4 z = {0.f, 0.f, 0.f, 0.f};
        #pragma unroll
        for (int mf = 0; mf < 4; ++mf) { C[mf][0] = z; C[mf][1] = z; }
    }
    // conv n-fragment pair base: conv5 wave-pairs (0,1)->0, (2,3)->2; conv3 wave4->0, wave5->2
    const int nf0c = (wv < 4) ? (wv & 2) : ((wv - 4) * 2);
    if (wv < 4) {
        if ((wv & 1) == 0) {                 // waves 0,2: conv5 taps 0-12 -> write partials
            conv2<5, 2, 64, 0, 13>(s_xlp, wb5f, m16, kg, ln, nf0c, C);
            float* pp = s_part + (wv >> 1) * PARTN;
            #pragma unroll
            for (int mf = 0; mf < 4; ++mf) {
                #pragma unroll
                for (int q = 0; q < 2; ++q) {
                    #pragma unroll
                    for (int rg = 0; rg < 4; ++rg) {
                        int lp = mf * 16 + kg * 4 + rg;
                        if (lp < 49) pp[lp * 33 + q * 16 + m16] = C[mf][q][rg];
                    }
                }
            }
        } else {                             // waves 1,3: conv5 taps 13-24
            conv2<5, 2, 64, 13, 25>(s_xlp, wb5f, m16, kg, ln, nf0c, C);
        }
    } else if (wv < 6) {                     // waves 4,5: conv3 full
        conv2<3, 1, 0, 0, 9>(s_xlp, wb3f, m16, kg, ln, nf0c, C);
    } else {                                 // waves 6,7: c_aggr (+ gdot on 7)
        const f32x4 z = {0.f, 0.f, 0.f, 0.f};
        bf16x8 aH[4];
        #pragma unroll
        for (int ks = 0; ks < 4; ++ks) {
            bf16x8 tt = {0,0,0,0,0,0,0,0};
            if (m16 == 0) tt = *(const bf16x8*)&s_hb[ks * 32 + kg * 8];
            aH[ks] = tt;
        }
        const int nfb = (wv - 6) * 16;
        #pragma unroll 2
        for (int it = 0; it < 8; ++it) {
            int nf0 = nfb + it * 2;
            f32x4 a0 = z, a1 = z;
            #pragma unroll
            for (int ks = 0; ks < 4; ++ks) {
                bf16x8 bb0 = *(const bf16x8*)(cwf + (((nf0)     * 4 + ks) * 64 + ln) * 8);
                bf16x8 bb1 = *(const bf16x8*)(cwf + (((nf0 + 1) * 4 + ks) * 64 + ln) * 8);
                a0 = __builtin_amdgcn_mfma_f32_16x16x32_bf16(aH[ks], bb0, a0, 0, 0, 0);
                a1 = __builtin_amdgcn_mfma_f32_16x16x32_bf16(aH[ks], bb1, a1, 0, 0, 0);
            }
            if (kg == 0) {
                int c0 = nf0 * 16 + m16;
                s_ca[c0] = sigmoidf_(a0[0] + 2.f * cb[c0]);
                int c1 = c0 + 16;
                s_ca[c1] = sigmoidf_(a1[0] + 2.f * cb[c1]);
            }
        }
        if (wv == 7) {
            float p = s_g[ln] * sw[128 + ln] + s_g[128 + ln] * sw[256 + ln]
                    + s_g[ln + 64] * sw[128 + ln + 64] + s_g[128 + ln + 64] * sw[256 + ln + 64];
            #pragma unroll
            for (int off = 32; off > 0; off >>= 1) p += __shfl_xor(p, off);
            if (ln == 0) s_gdot[0] = p;
        }
    }
    // conv3 epilogue can run before the merge barrier (independent of partials)
    if (wv == 4 || wv == 5) {
        const float bi0 = b3[nf0c * 16 + m16], bi1 = b3[(nf0c + 1) * 16 + m16];
        const float sw0 = sw[nf0c * 16 + m16], sw1 = sw[(nf0c + 1) * 16 + m16];
        #pragma unroll
        for (int mf = 0; mf < 4; ++mf) {
            #pragma unroll
            for (int rg = 0; rg < 4; ++rg) {
                int lp = mf * 16 + kg * 4 + rg;
                float v = star_relu(C[mf][0][rg] + bi0, scale, sbias) * sw0
                        + star_relu(C[mf][1][rg] + bi1, scale, sbias) * sw1;
                v = (lp < 49) ? v : 0.f;
                v += __shfl_xor(v, 1);
                v += __shfl_xor(v, 2);
                v += __shfl_xor(v, 4);
                v += __shfl_xor(v, 8);
                if (m16 == 0 && lp < 49) s_spw[(wv - 2) * 64 + lp] = v;   // slots 2,3
            }
        }
    }
    __syncthreads();

    // ---- P5b: conv5 merge + epilogue (waves 1,3) ----
    if (wv == 1 || wv == 3) {
        const float* pp = s_part + (wv >> 1) * PARTN;
        const int oc0 = nf0c * 16 + m16, oc1 = oc0 + 16;
        const float bi0 = b5[oc0], bi1 = b5[oc1];
        const float sw0 = sw[64 + oc0], sw1 = sw[64 + oc1];
        #pragma unroll
        for (int mf = 0; mf < 4; ++mf) {
            #pragma unroll
            for (int rg = 0; rg < 4; ++rg) {
                int lp = mf * 16 + kg * 4 + rg;
                int lps = min(lp, 48);
                float c0 = C[mf][0][rg] + pp[lps * 33 + m16];
                float c1 = C[mf][1][rg] + pp[lps * 33 + 16 + m16];
                float v = star_relu(c0 + bi0, scale, sbias) * sw0
                        + star_relu(c1 + bi1, scale, sbias) * sw1;
                v = (lp < 49) ? v : 0.f;
                v += __shfl_xor(v, 1);
                v += __shfl_xor(v, 2);
                v += __shfl_xor(v, 4);
                v += __shfl_xor(v, 8);
                if (m16 == 0 && lp < 49) s_spw[(wv >> 1) * 64 + lp] = v;  // slots 0,1
            }
        }
    }
    __syncthreads();

    // ---- P6: spatial gate ----
    if (t < 49) {
        float s = s_gdot[0] + sb[0];
        #pragma unroll
        for (int w = 0; w < 4; ++w) s += s_spw[w * 64 + t];
        s_sp[t] = sigmoidf_(s);
    }
    __syncthreads();

    // ---- P7: out = x * ca[c] * sp[l] ----
    {
        const float4* x4 = (const float4*)(x + (size_t)b * (L_ * C_));
        float4* o4 = (float4*)(out + (size_t)b * (L_ * C_));
        const int c4 = t & 127;
        const float4 cv = *(const float4*)&s_ca[c4 * 4];
        for (int i = t; i < 49 * 128; i += 512) {
            int l = i >> 7;
            float4 xv = x4[i];
            float g = s_sp[l];
            float4 ov;
            ov.x = xv.x * cv.x * g;
            ov.y = xv.y * cv.y * g;
            ov.z = xv.z * cv.z * g;
            ov.w = xv.w * cv.w * g;
            o4[i] = ov;
        }
    }
}

extern "C" void kernel_launch(void* const* d_in, const int* in_sizes, int n_in,
                              void* d_out, int out_size, void* d_ws, size_t ws_size,
                              hipStream_t stream) {
    (void)in_sizes; (void)n_in; (void)ws_size; (void)out_size;
    const float* x    = (const float*)d_in[0];
    const float* g_w  = (const float*)d_in[1];
    const float* l_w  = (const float*)d_in[2];
    const float* w3   = (const float*)d_in[3];
    const float* b3   = (const float*)d_in[4];
    const float* w5   = (const float*)d_in[5];
    const float* b5   = (const float*)d_in[6];
    const float* cw   = (const float*)d_in[7];
    const float* cb   = (const float*)d_in[8];
    const float* sw   = (const float*)d_in[9];
    const float* sb   = (const float*)d_in[10];
    const float* ssc  = (const float*)d_in[11];
    const float* sbi  = (const float*)d_in[12];
    float* outp = (float*)d_out;
    unsigned short* ws = (unsigned short*)d_ws;

    cvt_weights<<<dim3(512), dim3(256), 0, stream>>>(l_w, w3, w5, g_w, cw, ws);
    mafn_fused<<<dim3(B_), dim3(512), 0, stream>>>(
        x, b3, b5, cb, sw, sb, ssc, sbi, ws, outp);
}

// Round 12
// 688.444 us; speedup vs baseline: 1.0993x; 1.0993x over previous
//
#include <hip/hip_runtime.h>
#include <math.h>

#define B_ 8192
#define L_ 49
#define C_ 512
#define R_ 128

typedef short   bf16x8 __attribute__((ext_vector_type(8)));
typedef unsigned short u16x8 __attribute__((ext_vector_type(8)));
typedef float   f32x4  __attribute__((ext_vector_type(4)));

// ws layout (ushort elements) — ALL weights wave-fragment-contiguous
// lwf : [nt=8][ks=16][lane=64][8]   = lw[nt*16+(lane&15)][ks*32+(lane>>4)*8+j]
// gwf : same packing of g_reduce_w
// wb3f: [tap=9][f=4][ks=2][lane=64][8]  = w3[f*16+(lane&15)][ks*32+(lane>>4)*8+j][tap]
// wb5f: [tap=25][f=4][ks=2][lane=64][8] = w5[...][tap]
// cwf : [r8=16][c=512][8]           = cw[c][r8*8+j]
#define WS_LWF   0           // 65536
#define WS_WB3F  65536       // 36864
#define WS_WB5F  102400      // 102400
#define WS_GWF   204800      // 65536
#define WS_CWF   270336      // 65536

// shared memory layout (bytes), total 44304 -> 3 blocks/CU at launch_bounds(512,6)
#define SM_XB    0           // ush[49][256] swizzled, 25088
#define SM_XLB   25088       // ush[50][128] swizzled, 12800 | overlay P1/P2: maxb+sumf
#define SM_MAXB  25088       //   bf16 maxb[8][256] = 4096
#define SM_SUMF  29184       //   f32 sumf[8][256]  = 8192
#define SM_GA    37888       // bf16 ga[2][256] = 1024
#define SM_G     38912       // f32 g[2][128] = 1024
#define SM_CA    39936       // f32 ca[512] = 2048
#define SM_SPW   41984       // f32 spw[8][64] = 2048
#define SM_SP    44032       // f32[64]
#define SM_GDOT  44288       // f32[4]
#define SM_TOT   44304

__device__ __forceinline__ float bf2f(unsigned short u) {
    union { float f; unsigned int i; } v; v.i = ((unsigned int)u) << 16; return v.f;
}
__device__ __forceinline__ unsigned short f2bf(float f) {
    union { float f; unsigned int i; } v; v.f = f;
    unsigned int r = v.i + 0x7fffu + ((v.i >> 16) & 1u);
    return (unsigned short)(r >> 16);
}
__device__ __forceinline__ float star_relu(float x, float sc, float bi) {
    float r = fmaxf(x, 0.f);
    return sc * r * r + bi;
}
__device__ __forceinline__ float sigmoidf_(float x) {
    return 1.f / (1.f + __expf(-x));
}

// ---------------- pre-pass: convert + repack weights to fragment-contiguous bf16 ----------------
__global__ void cvt_weights(const float* __restrict__ lw, const float* __restrict__ w3,
                            const float* __restrict__ w5, const float* __restrict__ gw,
                            const float* __restrict__ cw, unsigned short* __restrict__ ws)
{
    int t = blockIdx.x * blockDim.x + threadIdx.x;
    int stride = gridDim.x * blockDim.x;
    // lwf / gwf: i = (((nt*16+ks)*64)+lane)*8 + j
    for (int i = t; i < 65536; i += stride) {
        int j = i & 7, lane = (i >> 3) & 63, ks = (i >> 9) & 15, nt = i >> 13;
        int n = nt * 16 + (lane & 15);
        int k = ks * 32 + (lane >> 4) * 8 + j;
        ws[WS_LWF + i] = f2bf(lw[n * 512 + k]);
        ws[WS_GWF + i] = f2bf(gw[n * 512 + k]);
    }
    // cwf: i = (r8*512 + c)*8 + j  -> cw[c][r8*8+j]
    for (int i = t; i < 65536; i += stride) {
        int j = i & 7, c = (i >> 3) & 511, r8 = i >> 12;
        ws[WS_CWF + i] = f2bf(cw[c * 128 + r8 * 8 + j]);
    }
    // wb3f: i = (((tap*4+f)*2+ks)*64+lane)*8 + j -> w3[oc][ic][tap]
    for (int i = t; i < 36864; i += stride) {
        int j = i & 7, lane = (i >> 3) & 63, ks = (i >> 9) & 1, f = (i >> 10) & 3, tap = i >> 12;
        int oc = f * 16 + (lane & 15);
        int ic = ks * 32 + (lane >> 4) * 8 + j;
        ws[WS_WB3F + i] = f2bf(w3[(oc * 64 + ic) * 9 + tap]);
    }
    // wb5f: same with 25 taps
    for (int i = t; i < 102400; i += stride) {
        int j = i & 7, lane = (i >> 3) & 63, ks = (i >> 9) & 1, f = (i >> 10) & 3, tap = i >> 12;
        int oc = f * 16 + (lane & 15);
        int ic = ks * 32 + (lane >> 4) * 8 + j;
        ws[WS_WB5F + i] = f2bf(w5[(oc * 64 + ic) * 25 + tap]);
    }
}

// ---------------- conv tap-GEMM body. Invalid taps read zeroed row 49. ----------------
// wtbf fragment layout: ((tap*4+f)*2+ks)*512 + ln*8
template <int NTAP, int KD, int PAD, int COLBASE>
__device__ __forceinline__ void conv_mfma(const unsigned short* __restrict__ s_xlb,
                                          const unsigned short* __restrict__ wtbf,
                                          int m16, int kg, int ln, int f, f32x4 C[4])
{
    int lp_[4], i_[4], j_[4];
    #pragma unroll
    for (int mf = 0; mf < 4; ++mf) {
        lp_[mf] = mf * 16 + m16;
        i_[mf] = lp_[mf] / 7;
        j_[mf] = lp_[mf] % 7;
    }
    #pragma unroll
    for (int tap = 0; tap < NTAP; ++tap) {
        const int dy = tap / KD - PAD, dx = tap % KD - PAD;
        int lc[4];
        #pragma unroll
        for (int mf = 0; mf < 4; ++mf) {
            int ii = i_[mf] + dy, jj = j_[mf] + dx;
            bool v = (lp_[mf] < 49) & (ii >= 0) & (ii < 7) & (jj >= 0) & (jj < 7);
            lc[mf] = v ? (ii * 7 + jj) : 49;              // row 49 is all zeros
        }
        #pragma unroll
        for (int ks = 0; ks < 2; ++ks) {
            bf16x8 bb = *(const bf16x8*)(wtbf + ((tap * 4 + f) * 2 + ks) * 512 + ln * 8);
            #pragma unroll
            for (int mf = 0; mf < 4; ++mf) {
                int chunk = ((COLBASE >> 3) + ks * 4 + kg) ^ (lc[mf] & 7);
                bf16x8 a = *(const bf16x8*)&s_xlb[lc[mf] * 128 + chunk * 8];
                C[mf] = __builtin_amdgcn_mfma_f32_16x16x32_bf16(a, bb, C[mf], 0, 0, 0);
            }
        }
    }
}

// ---------------- main fused kernel: one block per batch, target 3 blocks/CU ----------------
__global__ __launch_bounds__(512, 6)
void mafn_fused(const float* __restrict__ x,
                const float* __restrict__ b3, const float* __restrict__ b5,
                const float* __restrict__ cb, const float* __restrict__ sw,
                const float* __restrict__ sb, const float* __restrict__ ssc,
                const float* __restrict__ sbi,
                const unsigned short* __restrict__ ws,
                float* __restrict__ out)
{
    __shared__ __align__(16) unsigned char smem[SM_TOT];
    unsigned short* s_xb   = (unsigned short*)(smem + SM_XB);
    unsigned short* s_xlb  = (unsigned short*)(smem + SM_XLB);
    unsigned short* s_maxb = (unsigned short*)(smem + SM_MAXB);
    float*          s_sumf = (float*)(smem + SM_SUMF);
    unsigned short* s_ga   = (unsigned short*)(smem + SM_GA);
    float*          s_g    = (float*)(smem + SM_G);
    float*          s_ca   = (float*)(smem + SM_CA);
    float*          s_spw  = (float*)(smem + SM_SPW);
    float*          s_sp   = (float*)(smem + SM_SP);
    float*          s_gdot = (float*)(smem + SM_GDOT);

    const int b = blockIdx.x, t = threadIdx.x;
    const int wv = t >> 6, ln = t & 63;
    const int m16 = ln & 15, kg = ln >> 4;
    const float scale = ssc[0], sbias = sbi[0];

    const unsigned short* lwf  = ws + WS_LWF;
    const unsigned short* wb3f = ws + WS_WB3F;
    const unsigned short* wb5f = ws + WS_WB5F;
    const unsigned short* gwf  = ws + WS_GWF;
    const unsigned short* cwf  = ws + WS_CWF;

    f32x4 accA[4];       // x_l accumulators: this wave's n-fragment (n = wv*16+m16)
    f32x4 accG;          // g accumulator: this wave's n-fragment
    {
        const f32x4 z = {0.f, 0.f, 0.f, 0.f};
        #pragma unroll
        for (int mf = 0; mf < 4; ++mf) accA[mf] = z;
        accG = z;
    }

    const int l0 = wv * 6;
    const int nl = (wv < 7) ? 6 : 7;      // rows 42..48 for wave 7

    // ================= K-split halves: P1 load / P2 reduce / P3 GEMMs =================
    #pragma unroll 1
    for (int h = 0; h < 2; ++h) {
        // ---- P1: load x half (f32), partials, bf16 -> swizzled LDS ----
        {
            const float4* x4 = (const float4*)(x + (size_t)b * (L_ * C_)) + h * 64;
            float4 mx = {-3.4e38f, -3.4e38f, -3.4e38f, -3.4e38f};
            float4 sm = {0.f, 0.f, 0.f, 0.f};
            for (int li = 0; li < nl; ++li) {
                int l = l0 + li;
                float4 v = x4[l * 128 + ln];
                mx.x = fmaxf(mx.x, v.x); mx.y = fmaxf(mx.y, v.y);
                mx.z = fmaxf(mx.z, v.z); mx.w = fmaxf(mx.w, v.w);
                sm.x += v.x; sm.y += v.y; sm.z += v.z; sm.w += v.w;
                ushort4 p;
                p.x = f2bf(v.x); p.y = f2bf(v.y); p.z = f2bf(v.z); p.w = f2bf(v.w);
                int chunk = (ln >> 1) ^ (l & 7);
                *(ushort4*)&s_xb[l * 256 + chunk * 8 + (ln & 1) * 4] = p;
            }
            ushort4 pm;
            pm.x = f2bf(mx.x); pm.y = f2bf(mx.y); pm.z = f2bf(mx.z); pm.w = f2bf(mx.w);
            *(ushort4*)&s_maxb[wv * 256 + ln * 4] = pm;
            *(float4*)&s_sumf[wv * 256 + ln * 4] = sm;
        }
        __syncthreads();

        // ---- P2: finalize max/avg for this half -> bf16 A rows ----
        {
            if (t < 256) {
                int c = t;
                float m = bf2f(s_maxb[c]);
                #pragma unroll
                for (int i = 1; i < 8; ++i) m = fmaxf(m, bf2f(s_maxb[i * 256 + c]));
                s_ga[c] = f2bf(m);                       // exact: m already a bf16 value
            } else {
                int c = t - 256;
                float s = 0.f;
                #pragma unroll
                for (int i = 0; i < 8; ++i) s += s_sumf[i * 256 + c];
                s_ga[256 + c] = f2bf(s * (1.f / 49.f));
            }
        }
        __syncthreads();

        // ---- P3: all 8 waves: x_l MFMA (1 n-frag each), then g MFMA (1 n-frag each) ----
        {
            int rowA[4];
            #pragma unroll
            for (int mf = 0; mf < 4; ++mf) rowA[mf] = min(mf * 16 + m16, 48);
            #pragma unroll 2
            for (int ks = 0; ks < 8; ++ks) {
                bf16x8 bb = *(const bf16x8*)(lwf + (wv * 16 + h * 8 + ks) * 512 + ln * 8);
                #pragma unroll
                for (int mf = 0; mf < 4; ++mf) {
                    int chunk = (ks * 4 + kg) ^ (rowA[mf] & 7);
                    bf16x8 a = *(const bf16x8*)&s_xb[rowA[mf] * 256 + chunk * 8];
                    accA[mf] = __builtin_amdgcn_mfma_f32_16x16x32_bf16(a, bb, accA[mf], 0, 0, 0);
                }
            }
            const bf16x8 zz = {0,0,0,0,0,0,0,0};
            #pragma unroll 4
            for (int ks = 0; ks < 8; ++ks) {
                bf16x8 a = (m16 < 2) ? *(const bf16x8*)&s_ga[m16 * 256 + ks * 32 + kg * 8] : zz;
                bf16x8 bb = *(const bf16x8*)(gwf + (wv * 16 + h * 8 + ks) * 512 + ln * 8);
                accG = __builtin_amdgcn_mfma_f32_16x16x32_bf16(a, bb, accG, 0, 0, 0);
            }
        }
        __syncthreads();
    }

    // ---- P4: store x_l bf16 (swizzled, all waves) + g (kg==0 lanes) ----
    {
        if (t < 64) ((unsigned int*)(s_xlb + 49 * 128))[t] = 0;   // zero row 49
        const int n = wv * 16 + m16;
        #pragma unroll
        for (int mf = 0; mf < 4; ++mf) {
            #pragma unroll
            for (int rg = 0; rg < 4; ++rg) {
                int lp = mf * 16 + kg * 4 + rg;
                if (lp < 49) {
                    int idx = lp * 128 + ((((n >> 3) ^ (lp & 7)) << 3) + (n & 7));
                    s_xlb[idx] = f2bf(accA[mf][rg]);
                }
            }
        }
        if (kg == 0) {
            s_g[n]       = star_relu(accG[0], scale, sbias);   // row 0 = max -> g1
            s_g[128 + n] = star_relu(accG[1], scale, sbias);   // row 1 = avg -> g2
        }
    }
    __syncthreads();

    // ---- P5: waves 0-3: conv5 full  ||  waves 4-7: conv3 full + c_aggr + gdot ----
    const int f_ = wv & 3;
    const int oc_ = f_ * 16 + m16;
    {
        f32x4 C[4];
        const f32x4 z = {0.f, 0.f, 0.f, 0.f};
        #pragma unroll
        for (int mf = 0; mf < 4; ++mf) C[mf] = z;

        if (wv < 4) {
            conv_mfma<25, 5, 2, 64>(s_xlb, wb5f, m16, kg, ln, f_, C);   // 200 MFMA
        } else {
            conv_mfma< 9, 3, 1,  0>(s_xlb, wb3f, m16, kg, ln, f_, C);   // 72 MFMA
            // c_aggr: waves 4-7 = 256 threads, 2 channels each; cwf[r8][c][8] coalesced
            const int idx = t - 256;
            #pragma unroll
            for (int half = 0; half < 2; ++half) {
                int c = idx + half * 256;
                float a0 = 0.f, a1 = 0.f;
                #pragma unroll 4
                for (int r8 = 0; r8 < 16; ++r8) {
                    u16x8 w = *(const u16x8*)(cwf + r8 * 4096 + c * 8);
                    float p = 0.f;
                    #pragma unroll
                    for (int k = 0; k < 8; ++k)
                        p += bf2f(w[k]) * (s_g[r8 * 8 + k] + s_g[128 + r8 * 8 + k]);
                    if (r8 & 1) a1 += p; else a0 += p;
                }
                s_ca[c] = sigmoidf_(a0 + a1 + 2.f * cb[c]);
            }
            if (wv == 7) {
                float p = s_g[ln] * sw[128 + ln] + s_g[128 + ln] * sw[256 + ln]
                        + s_g[ln + 64] * sw[128 + ln + 64] + s_g[128 + ln + 64] * sw[256 + ln + 64];
                #pragma unroll
                for (int off = 32; off > 0; off >>= 1) p += __shfl_xor(p, off);
                if (ln == 0) s_gdot[0] = p;
            }
        }

        // epilogue: star_relu + sw-dot, reduce over this wave's 16 channels
        const bool is5 = (wv < 4);
        const int ch = is5 ? 64 + oc_ : oc_;
        const float bias = is5 ? b5[oc_] : b3[oc_];
        const float sww = sw[ch];
        #pragma unroll
        for (int mf = 0; mf < 4; ++mf) {
            #pragma unroll
            for (int rg = 0; rg < 4; ++rg) {
                int lp = mf * 16 + kg * 4 + rg;
                float v = (lp < 49) ? star_relu(C[mf][rg] + bias, scale, sbias) * sww : 0.f;
                v += __shfl_xor(v, 1);
                v += __shfl_xor(v, 2);
                v += __shfl_xor(v, 4);
                v += __shfl_xor(v, 8);
                if (m16 == 0 && lp < 49) s_spw[wv * 64 + lp] = v;
            }
        }
    }
    __syncthreads();

    // ---- P6: spatial gate (sum 8 wave partials) ----
    if (t < 49) {
        float s = s_gdot[0] + sb[0];
        #pragma unroll
        for (int w = 0; w < 8; ++w) s += s_spw[w * 64 + t];
        s_sp[t] = sigmoidf_(s);
    }
    __syncthreads();

    // ---- P7: out = x * ca[c] * sp[l] (x re-read f32, L2-hot) ----
    {
        const float4* x4 = (const float4*)(x + (size_t)b * (L_ * C_));
        float4* o4 = (float4*)(out + (size_t)b * (L_ * C_));
        const float4* ca4 = (const float4*)s_ca;
        for (int i = t; i < 49 * 128; i += 512) {
            int l = i >> 7, c4 = i & 127;
            float4 xv = x4[i];
            float g = s_sp[l];
            float4 cv = ca4[c4];
            float4 ov;
            ov.x = xv.x * cv.x * g;
            ov.y = xv.y * cv.y * g;
            ov.z = xv.z * cv.z * g;
            ov.w = xv.w * cv.w * g;
            o4[i] = ov;
        }
    }
}

extern "C" void kernel_launch(void* const* d_in, const int* in_sizes, int n_in,
                              void* d_out, int out_size, void* d_ws, size_t ws_size,
                              hipStream_t stream) {
    (void)in_sizes; (void)n_in; (void)ws_size; (void)out_size;
    const float* x    = (const float*)d_in[0];
    const float* g_w  = (const float*)d_in[1];
    const float* l_w  = (const float*)d_in[2];
    const float* w3   = (const float*)d_in[3];
    const float* b3   = (const float*)d_in[4];
    const float* w5   = (const float*)d_in[5];
    const float* b5   = (const float*)d_in[6];
    const float* cw   = (const float*)d_in[7];
    const float* cb   = (const float*)d_in[8];
    const float* sw   = (const float*)d_in[9];
    const float* sb   = (const float*)d_in[10];
    const float* ssc  = (const float*)d_in[11];
    const float* sbi  = (const float*)d_in[12];
    float* outp = (float*)d_out;
    unsigned short* ws = (unsigned short*)d_ws;

    cvt_weights<<<dim3(512), dim3(256), 0, stream>>>(l_w, w3, w5, g_w, cw, ws);
    mafn_fused<<<dim3(B_), dim3(512), 0, stream>>>(
        x, b3, b5, cb, sw, sb, ssc, sbi, ws, outp);
}